// Round 1
// baseline (1237.973 us; speedup 1.0000x reference)
//
#include <hip/hip_runtime.h>
#include <math.h>

#define B_   16
#define C_   256
#define T_   2048
#define CQK_ 32
#define OTOT 320   // CQK + CQK + C

// ws layout (floats): W_all [320*256], b_all [320], QKV [B][320][T]
#define B_ALL_OFF (OTOT * C_)          // 81920
#define QKV_OFF   (OTOT * C_ + 320)    // 82240 (16B-aligned in floats)

// ---------------------------------------------------------------------------
// Kernel 0: pack Wq/Wk/Wv -> W_all [320][256], bq/bk/bv -> b_all [320]
// ---------------------------------------------------------------------------
__global__ __launch_bounds__(256) void pack_kernel(
    const float* __restrict__ Wq, const float* __restrict__ bq,
    const float* __restrict__ Wk, const float* __restrict__ bk,
    const float* __restrict__ Wv, const float* __restrict__ bv,
    float* __restrict__ ws) {
  int idx = blockIdx.x * 256 + threadIdx.x;   // grid = 320 blocks -> 81920
  float* W_all = ws;
  float* b_all = ws + B_ALL_OFF;
  if (idx < OTOT * C_) {
    int o = idx / C_, c = idx % C_;
    float v;
    if (o < CQK_)            v = Wq[o * C_ + c];
    else if (o < 2 * CQK_)   v = Wk[(o - CQK_) * C_ + c];
    else                     v = Wv[(o - 2 * CQK_) * C_ + c];
    W_all[idx] = v;
  }
  if (idx < OTOT) {
    float v;
    if (idx < CQK_)          v = bq[idx];
    else if (idx < 2 * CQK_) v = bk[idx - CQK_];
    else                     v = bv[idx - 2 * CQK_];
    b_all[idx] = v;
  }
}

// ---------------------------------------------------------------------------
// Kernel 1: QKV projection.  QKV[b][o][t] = sum_c W_all[o][c]*x[b][c][t] + b[o]
// One block per (b, 64-wide t tile). x-tile staged in 64KB LDS.
// Thread: t-lane = tid&63, row-group og = tid>>6 (wave-uniform -> s_load W).
// ---------------------------------------------------------------------------
__global__ __launch_bounds__(256) void proj_kernel(
    const float* __restrict__ x, const float* __restrict__ ws,
    float* __restrict__ qkv) {
  __shared__ float xs[C_ * 64];   // [c][t], 64 KB
  const int b  = blockIdx.y;
  const int t0 = blockIdx.x * 64;
  const int tid = threadIdx.x;
  const float* xb = x + (size_t)b * C_ * T_;

  // stage x[b][:, t0:t0+64], coalesced float4
  #pragma unroll
  for (int r = 0; r < 16; ++r) {
    int idx = r * 256 + tid;        // 4096 float4
    int c = idx >> 4, f = idx & 15;
    float4 v = *(const float4*)(xb + (size_t)c * T_ + t0 + f * 4);
    *(float4*)(xs + c * 64 + f * 4) = v;
  }
  __syncthreads();

  const float* W_all = ws;
  const float* b_all = ws + B_ALL_OFF;
  const int t  = tid & 63;
  const int og = __builtin_amdgcn_readfirstlane(tid >> 6);   // 0..3, wave-uniform

  for (int chunk = 0; chunk < 4; ++chunk) {
    const int obase = chunk * 80 + og * 20;
    float acc[20];
    #pragma unroll
    for (int i = 0; i < 20; ++i) acc[i] = 0.f;
    for (int c = 0; c < C_; ++c) {
      float xv = xs[c * 64 + t];
      #pragma unroll
      for (int i = 0; i < 20; ++i)
        acc[i] += W_all[(obase + i) * C_ + c] * xv;   // wave-uniform -> s_load
    }
    #pragma unroll
    for (int i = 0; i < 20; ++i) {
      int o = obase + i;
      qkv[((size_t)b * OTOT + o) * T_ + t0 + t] = acc[i] + b_all[o];
    }
  }
}

// ---------------------------------------------------------------------------
// Kernel 2: fused attention + residual.
// Block = (b, 64-query tile). Stream s in tiles of 32.
// No max-subtraction (|scores| <~ 30 << 88, fp32 exp safe).
// Phase2: S = Q^T K, exp -> Ps (LDS).  Phase3: acc[q][c] += P * V (V transposed
// in LDS -> wave-uniform broadcast reads). Epilogue: /sum + x, coalesced in t.
// ---------------------------------------------------------------------------
__global__ __launch_bounds__(256) void attn_kernel(
    const float* __restrict__ x, const float* __restrict__ qkv,
    float* __restrict__ out) {
  __shared__ float Qs[CQK_ * 68];    // [c][q], stride 68
  __shared__ float Ks[CQK_ * 36];    // [c][s], stride 36
  __shared__ float Ps[64 * 33];      // [q][s], stride 33
  __shared__ float Vs[32 * 260];     // [s][c], stride 260 (transposed!)
  __shared__ float sums[64 * 9];
  __shared__ float inv_s[64];

  const int id = blockIdx.x;
  const int b  = ((id & 7) << 1) | ((id >> 3) & 1);  // XCD swizzle: 2 batches/XCD
  const int qt = id >> 4;
  const int t0 = qt * 64;
  const int tid = threadIdx.x;

  const float* Qg = qkv + (size_t)b * OTOT * T_;
  const float* Kg = Qg + (size_t)CQK_ * T_;
  const float* Vg = Qg + (size_t)2 * CQK_ * T_;

  // stage Q tile [32][64]
  #pragma unroll
  for (int rr = 0; rr < 2; ++rr) {
    int idx = rr * 256 + tid;       // 512 float4
    int cc = idx >> 4, f = idx & 15;
    float4 v = *(const float4*)(Qg + (size_t)cc * T_ + t0 + f * 4);
    *(float4*)(Qs + cc * 68 + f * 4) = v;
  }

  float acc[64];
  #pragma unroll
  for (int j = 0; j < 64; ++j) acc[j] = 0.f;
  float psum[2] = {0.f, 0.f};

  const int sg = tid & 7;        // phase-2: 4 s-cols
  const int qg = tid >> 3;       // phase-2: 2 q-rows
  const int q0 = qg * 2;
  const int s0 = sg * 4;
  const int ql = tid & 63;       // phase-3: query lane
  const int cb = (tid >> 6) * 64;

  for (int it = 0; it < 64; ++it) {
    const int sb = it * 32;
    __syncthreads();   // previous iteration done with Ks/Vs/Ps

    // stage K tile [32][32]
    {
      int cc = tid >> 3, f = tid & 7;
      float4 v = *(const float4*)(Kg + (size_t)cc * T_ + sb + f * 4);
      *(float4*)(Ks + cc * 36 + f * 4) = v;
    }
    // stage V tile transposed: Vs[s][c]
    #pragma unroll
    for (int rr = 0; rr < 8; ++rr) {
      int idx = rr * 256 + tid;   // 2048 float4
      int c = idx >> 3, f = idx & 7;
      float4 v = *(const float4*)(Vg + (size_t)c * T_ + sb + f * 4);
      Vs[(f * 4 + 0) * 260 + c] = v.x;
      Vs[(f * 4 + 1) * 260 + c] = v.y;
      Vs[(f * 4 + 2) * 260 + c] = v.z;
      Vs[(f * 4 + 3) * 260 + c] = v.w;
    }
    __syncthreads();

    // phase 2: S-tile + exp
    {
      float sa[2][4];
      #pragma unroll
      for (int iq = 0; iq < 2; ++iq)
        #pragma unroll
        for (int js = 0; js < 4; ++js) sa[iq][js] = 0.f;
      #pragma unroll 4
      for (int c = 0; c < CQK_; ++c) {
        float2 qv = *(const float2*)(Qs + c * 68 + q0);
        float4 kv = *(const float4*)(Ks + c * 36 + s0);
        sa[0][0] += qv.x * kv.x; sa[0][1] += qv.x * kv.y;
        sa[0][2] += qv.x * kv.z; sa[0][3] += qv.x * kv.w;
        sa[1][0] += qv.y * kv.x; sa[1][1] += qv.y * kv.y;
        sa[1][2] += qv.y * kv.z; sa[1][3] += qv.y * kv.w;
      }
      #pragma unroll
      for (int iq = 0; iq < 2; ++iq) {
        float rs = 0.f;
        #pragma unroll
        for (int js = 0; js < 4; ++js) {
          float e = __expf(sa[iq][js]);
          Ps[(q0 + iq) * 33 + s0 + js] = e;
          rs += e;
        }
        psum[iq] += rs;
      }
    }
    __syncthreads();

    // phase 3: acc[q][c] += P[q][s] * V[s][c]   (V reads wave-uniform)
    {
      const float* prow = Ps + ql * 33;
      for (int s = 0; s < 32; ++s) {
        float p = prow[s];
        const float* vrow = Vs + s * 260 + cb;
        #pragma unroll
        for (int j4 = 0; j4 < 16; ++j4) {
          float4 v = *(const float4*)(vrow + j4 * 4);
          acc[j4 * 4 + 0] += p * v.x;
          acc[j4 * 4 + 1] += p * v.y;
          acc[j4 * 4 + 2] += p * v.z;
          acc[j4 * 4 + 3] += p * v.w;
        }
      }
    }
  }

  // reduce row sums across the 8 s-groups
  __syncthreads();
  sums[(q0 + 0) * 9 + sg] = psum[0];
  sums[(q0 + 1) * 9 + sg] = psum[1];
  __syncthreads();
  if (tid < 64) {
    float tot = 0.f;
    #pragma unroll
    for (int k = 0; k < 8; ++k) tot += sums[tid * 9 + k];
    inv_s[tid] = 1.0f / tot;
  }
  __syncthreads();

  // epilogue: out = acc/sum + x, coalesced along t (lane = q)
  {
    const float inv = inv_s[ql];
    const float* xb = x   + (size_t)b * C_ * T_;
    float*       ob = out + (size_t)b * C_ * T_;
    #pragma unroll
    for (int j = 0; j < 64; ++j) {
      size_t a = (size_t)(cb + j) * T_ + t0 + ql;
      ob[a] = acc[j] * inv + xb[a];
    }
  }
}

// ---------------------------------------------------------------------------
extern "C" void kernel_launch(void* const* d_in, const int* in_sizes, int n_in,
                              void* d_out, int out_size, void* d_ws, size_t ws_size,
                              hipStream_t stream) {
  const float* x  = (const float*)d_in[0];
  const float* Wq = (const float*)d_in[1];
  const float* bq = (const float*)d_in[2];
  const float* Wk = (const float*)d_in[3];
  const float* bk = (const float*)d_in[4];
  const float* Wv = (const float*)d_in[5];
  const float* bv = (const float*)d_in[6];
  float* out = (float*)d_out;
  float* ws  = (float*)d_ws;
  float* qkv = ws + QKV_OFF;

  pack_kernel<<<320, 256, 0, stream>>>(Wq, bq, Wk, bk, Wv, bv, ws);
  proj_kernel<<<dim3(T_ / 64, B_), 256, 0, stream>>>(x, ws, qkv);
  attn_kernel<<<B_ * (T_ / 64), 256, 0, stream>>>(x, qkv, out);
}

// Round 2
// 274.410 us; speedup vs baseline: 4.5114x; 4.5114x over previous
//
#include <hip/hip_runtime.h>
#include <math.h>

typedef __attribute__((ext_vector_type(8)))  short          short8;
typedef __attribute__((ext_vector_type(8)))  unsigned short ushort8;
typedef __attribute__((ext_vector_type(16))) float          f32x16;

#define Bb 16
#define Cc 256
#define Tt 2048

// ---- workspace layout (bytes) ----
#define WT_OFF    0u                         // Wt fp32 [256 c][320 o]
#define BALL_OFF  327680u                    // fp32 [320]
#define QTHI_OFF  328960u                    // ushort [16][2048][32]  (bf16 bits, [t][c] layout)
#define QTLO_OFF  (QTHI_OFF + 2097152u)
#define KTHI_OFF  (QTLO_OFF + 2097152u)
#define KTLO_OFF  (KTHI_OFF + 2097152u)
#define VBF_OFF   (KTLO_OFF + 2097152u)      // ushort [16][256][2048] (bf16 bits, [c][t] layout)

__device__ __forceinline__ unsigned short f2bf(float f) {
  union { float f; unsigned u; } v; v.f = f;
  unsigned r = v.u + 0x7fffu + ((v.u >> 16) & 1u);   // RNE
  return (unsigned short)(r >> 16);
}
__device__ __forceinline__ float bf2f(unsigned short h) {
  union { unsigned u; float f; } v; v.u = ((unsigned)h) << 16;
  return v.f;
}

// ---------------------------------------------------------------------------
// pack: W^T fp32 [c][320] (so proj's 20 weights per c are contiguous) + bias
// ---------------------------------------------------------------------------
__global__ __launch_bounds__(256) void pack_kernel(
    const float* __restrict__ Wq, const float* __restrict__ bq,
    const float* __restrict__ Wk, const float* __restrict__ bk,
    const float* __restrict__ Wv, const float* __restrict__ bv,
    char* ws) {
  float* Wt   = (float*)(ws + WT_OFF);
  float* ball = (float*)(ws + BALL_OFF);
  int o = blockIdx.x, c = threadIdx.x;
  float v;
  if (o < 32)      v = Wq[o * 256 + c];
  else if (o < 64) v = Wk[(o - 32) * 256 + c];
  else             v = Wv[(o - 64) * 256 + c];
  Wt[c * 320 + o] = v;
  if (c == 0) ball[o] = (o < 32) ? bq[o] : (o < 64 ? bk[o - 32] : bv[o - 64]);
}

// ---------------------------------------------------------------------------
// proj: QKV[o][t] = sum_c W[o][c] x[c][t] + b[o], fp32 vector path.
// Outputs: Qt/Kt as [b][t][32] bf16 hi+lo (via LDS transpose), V as [b][c][t] bf16.
// Block = (t-tile 64, b). t = lane, og = wave (wave-uniform -> s_load 20
// CONTIGUOUS floats per c from W^T).
// ---------------------------------------------------------------------------
__global__ __launch_bounds__(256, 2) void proj_kernel(
    const float* __restrict__ x, char* ws) {
  __shared__ __align__(16) float xs[256 * 68];   // x tile [c][t]; reused as Q/K transpose buf

  const float* Wt   = (const float*)(ws + WT_OFF);
  const float* ball = (const float*)(ws + BALL_OFF);
  unsigned short* Qthi = (unsigned short*)(ws + QTHI_OFF);
  unsigned short* Qtlo = (unsigned short*)(ws + QTLO_OFF);
  unsigned short* Kthi = (unsigned short*)(ws + KTHI_OFF);
  unsigned short* Ktlo = (unsigned short*)(ws + KTLO_OFF);
  unsigned short* Vbf  = (unsigned short*)(ws + VBF_OFF);

  const int b  = blockIdx.y;
  const int t0 = blockIdx.x * 64;
  const int tid = threadIdx.x;
  const int t  = tid & 63;
  const int og = __builtin_amdgcn_readfirstlane(tid >> 6);

  // stage x[b][:, t0:t0+64] (coalesced float4)
  #pragma unroll
  for (int r = 0; r < 16; ++r) {
    int idx = r * 256 + tid;
    int c = idx >> 4, f = idx & 15;
    *(float4*)&xs[c * 68 + 4 * f] =
        *(const float4*)&x[((size_t)b * 256 + c) * 2048 + t0 + 4 * f];
  }
  __syncthreads();

  // chunks 1,2,3 (pure V rows), then chunk 0 (Q/K + some V) last so xs can be reused
  for (int ci = 0; ci < 3; ++ci) {
    const int chunk = ci + 1;
    const int obase = chunk * 80 + og * 20;
    float acc[20];
    #pragma unroll
    for (int i = 0; i < 20; ++i) acc[i] = 0.f;
    for (int c = 0; c < 256; ++c) {
      float xv = xs[c * 68 + t];
      const float* wrow = &Wt[c * 320 + obase];
      #pragma unroll
      for (int i = 0; i < 20; ++i) acc[i] += wrow[i] * xv;
    }
    #pragma unroll
    for (int i = 0; i < 20; ++i) {
      int o = obase + i;
      Vbf[((size_t)b * 256 + (o - 64)) * 2048 + t0 + t] = f2bf(acc[i] + ball[o]);
    }
  }

  // chunk 0: o in [og*20, og*20+20)
  {
    const int obase = og * 20;
    float acc[20];
    #pragma unroll
    for (int i = 0; i < 20; ++i) acc[i] = 0.f;
    for (int c = 0; c < 256; ++c) {
      float xv = xs[c * 68 + t];
      const float* wrow = &Wt[c * 320 + obase];
      #pragma unroll
      for (int i = 0; i < 20; ++i) acc[i] += wrow[i] * xv;
    }
    // V rows (o >= 64, only og==3 has them) stored directly
    #pragma unroll
    for (int i = 0; i < 20; ++i) {
      int o = obase + i;
      if (o >= 64)
        Vbf[((size_t)b * 256 + (o - 64)) * 2048 + t0 + t] = f2bf(acc[i] + ball[o]);
    }
    __syncthreads();   // all waves done reading xs
    #pragma unroll
    for (int i = 0; i < 20; ++i) {
      int o = obase + i;
      if (o < 64) xs[o * 68 + t] = acc[i] + ball[o];   // fp32 Q/K tile [o][t]
    }
    __syncthreads();
    // transpose out: Qt/Kt [t][c] bf16 hi/lo, coalesced ushort8 stores
    const int tt2 = tid >> 2, og4 = tid & 3;
    const size_t row = ((size_t)b * 2048 + t0 + tt2) * 32;
    unsigned short* ph = (og4 < 2) ? Qthi : Kthi;
    unsigned short* pl = (og4 < 2) ? Qtlo : Ktlo;
    const int colbase = (og4 & 1) * 16;
    #pragma unroll
    for (int g = 0; g < 2; ++g) {
      ushort8 vh, vl;
      #pragma unroll
      for (int j = 0; j < 8; ++j) {
        float v = xs[(og4 * 16 + g * 8 + j) * 68 + tt2];
        unsigned short h = f2bf(v);
        vh[j] = h;
        vl[j] = f2bf(v - bf2f(h));
      }
      *(ushort8*)&ph[row + colbase + g * 8] = vh;
      *(ushort8*)&pl[row + colbase + g * 8] = vl;
    }
  }
}

// ---------------------------------------------------------------------------
// attn: flash-style, MFMA 32x32x16 bf16.
// Block = (b, 64-q tile), s-tiles of 32, 64 iterations.
// QK: waves 0,1 (split-precision: Qh*Kh + Qh*Kl + Ql*Kh), exp in fp32,
// P -> bf16 in LDS. PV: all waves, D[c][q] orientation (A=V[c][s], B=P[q][s])
// so epilogue stores are coalesced along t.
// ---------------------------------------------------------------------------
__global__ __launch_bounds__(256, 2) void attn_kernel(
    const float* __restrict__ x, const char* __restrict__ ws,
    float* __restrict__ out) {
  __shared__ __align__(16) unsigned short Qsh[64 * 40], Qsl[64 * 40];
  __shared__ __align__(16) unsigned short Ksh[32 * 40], Ksl[32 * 40];
  __shared__ __align__(16) unsigned short Ps[64 * 40];
  __shared__ __align__(16) unsigned short Vs[256 * 40];
  __shared__ float sums[64];
  __shared__ float invs[64];

  const unsigned short* Qthi = (const unsigned short*)(ws + QTHI_OFF);
  const unsigned short* Qtlo = (const unsigned short*)(ws + QTLO_OFF);
  const unsigned short* Kthi = (const unsigned short*)(ws + KTHI_OFF);
  const unsigned short* Ktlo = (const unsigned short*)(ws + KTLO_OFF);

  const int id = blockIdx.x;
  const int b  = ((id & 7) << 1) | ((id >> 3) & 1);   // 2 batches per XCD
  const int qt = id >> 4;
  const int t0 = qt * 64;
  const int tid  = threadIdx.x;
  const int w    = tid >> 6;
  const int lane = tid & 63;
  const int m    = lane & 31;
  const int hh   = lane >> 5;

  const unsigned short* Vg =
      (const unsigned short*)(ws + VBF_OFF) + (size_t)b * 256 * 2048;

  // stage Q tile once: [64 q][32 c] hi+lo
  {
    int rr = tid >> 2, cq = tid & 3;
    size_t g = ((size_t)b * 2048 + t0 + rr) * 32 + cq * 8;
    *(ushort8*)&Qsh[rr * 40 + cq * 8] = *(const ushort8*)&Qthi[g];
    *(ushort8*)&Qsl[rr * 40 + cq * 8] = *(const ushort8*)&Qtlo[g];
  }

  f32x16 pacc[2][2];   // [q-tile n][c-tile mi]
  #pragma unroll
  for (int n = 0; n < 2; ++n)
    #pragma unroll
    for (int mi = 0; mi < 2; ++mi)
      #pragma unroll
      for (int r = 0; r < 16; ++r) pacc[n][mi][r] = 0.f;
  float sacc[16];
  #pragma unroll
  for (int r = 0; r < 16; ++r) sacc[r] = 0.f;

  for (int it = 0; it < 64; ++it) {
    const int sb = it * 32;
    __syncthreads();   // prev iter's PV done with Ks/Vs/Ps

    // stage K tile [32 s][32 c] hi+lo (direct ushort8, [t][c] global layout)
    {
      int p = tid >> 7, rr = (tid >> 2) & 31, cq = tid & 3;
      size_t g = ((size_t)b * 2048 + sb + rr) * 32 + cq * 8;
      const unsigned short* src = p ? Ktlo : Kthi;
      unsigned short* dst = p ? Ksl : Ksh;
      *(ushort8*)&dst[rr * 40 + cq * 8] = *(const ushort8*)&src[g];
    }
    // stage V tile [256 c][32 s] (direct ushort8 from [c][t] global layout)
    #pragma unroll
    for (int r = 0; r < 4; ++r) {
      int idx = r * 256 + tid;
      int c = idx >> 2, k = idx & 3;
      *(ushort8*)&Vs[c * 40 + k * 8] = *(const ushort8*)&Vg[(size_t)c * 2048 + sb + k * 8];
    }
    __syncthreads();

    if (w < 2) {   // QK + exp on waves 0,1 (wave w -> q rows 32w..32w+31)
      f32x16 qacc;
      #pragma unroll
      for (int r = 0; r < 16; ++r) qacc[r] = 0.f;
      #pragma unroll
      for (int ks = 0; ks < 2; ++ks) {
        short8 ah = *(const short8*)&Qsh[(32 * w + m) * 40 + ks * 16 + hh * 8];
        short8 al = *(const short8*)&Qsl[(32 * w + m) * 40 + ks * 16 + hh * 8];
        short8 bh = *(const short8*)&Ksh[m * 40 + ks * 16 + hh * 8];
        short8 bl = *(const short8*)&Ksl[m * 40 + ks * 16 + hh * 8];
        qacc = __builtin_amdgcn_mfma_f32_32x32x16_bf16(ah, bh, qacc, 0, 0, 0);
        qacc = __builtin_amdgcn_mfma_f32_32x32x16_bf16(ah, bl, qacc, 0, 0, 0);
        qacc = __builtin_amdgcn_mfma_f32_32x32x16_bf16(al, bh, qacc, 0, 0, 0);
      }
      #pragma unroll
      for (int r = 0; r < 16; ++r) {
        float e = __expf(qacc[r]);
        unsigned short hb = f2bf(e);
        sacc[r] += bf2f(hb);   // sum the rounded value -> exact normalization
        int q = 32 * w + (r & 3) + 8 * (r >> 2) + 4 * hh;
        Ps[q * 40 + m] = hb;
      }
    }
    __syncthreads();

    // PV: D[c][q] += V[c][s] * P[q][s]; wave w -> c-tiles {w, w+4}, both q-tiles
    #pragma unroll
    for (int ks = 0; ks < 2; ++ks) {
      short8 p0 = *(const short8*)&Ps[m * 40 + ks * 16 + hh * 8];
      short8 p1 = *(const short8*)&Ps[(32 + m) * 40 + ks * 16 + hh * 8];
      short8 v0 = *(const short8*)&Vs[(32 * w + m) * 40 + ks * 16 + hh * 8];
      short8 v1 = *(const short8*)&Vs[(32 * (w + 4) + m) * 40 + ks * 16 + hh * 8];
      pacc[0][0] = __builtin_amdgcn_mfma_f32_32x32x16_bf16(v0, p0, pacc[0][0], 0, 0, 0);
      pacc[0][1] = __builtin_amdgcn_mfma_f32_32x32x16_bf16(v1, p0, pacc[0][1], 0, 0, 0);
      pacc[1][0] = __builtin_amdgcn_mfma_f32_32x32x16_bf16(v0, p1, pacc[1][0], 0, 0, 0);
      pacc[1][1] = __builtin_amdgcn_mfma_f32_32x32x16_bf16(v1, p1, pacc[1][1], 0, 0, 0);
    }
  }

  // row sums -> inv
  if (w < 2) {
    #pragma unroll
    for (int r = 0; r < 16; ++r) {
      float v = sacc[r];
      #pragma unroll
      for (int off = 1; off < 32; off <<= 1) v += __shfl_xor(v, off, 64);
      if (m == 0) sums[32 * w + (r & 3) + 8 * (r >> 2) + 4 * hh] = v;
    }
  }
  __syncthreads();
  if (tid < 64) invs[tid] = 1.0f / sums[tid];
  __syncthreads();

  // epilogue: out = pacc/sum + x, coalesced along t (col = q)
  const float inv0 = invs[m], inv1 = invs[32 + m];
  #pragma unroll
  for (int n = 0; n < 2; ++n) {
    const float inv = n ? inv1 : inv0;
    const int q = 32 * n + m;
    #pragma unroll
    for (int mi = 0; mi < 2; ++mi) {
      const int cbase = 32 * (w + 4 * mi);
      #pragma unroll
      for (int r = 0; r < 16; ++r) {
        int c = cbase + (r & 3) + 8 * (r >> 2) + 4 * hh;
        size_t a = ((size_t)b * 256 + c) * 2048 + t0 + q;
        out[a] = pacc[n][mi][r] * inv + x[a];
      }
    }
  }
}

// ---------------------------------------------------------------------------
extern "C" void kernel_launch(void* const* d_in, const int* in_sizes, int n_in,
                              void* d_out, int out_size, void* d_ws, size_t ws_size,
                              hipStream_t stream) {
  const float* x  = (const float*)d_in[0];
  const float* Wq = (const float*)d_in[1];
  const float* bq = (const float*)d_in[2];
  const float* Wk = (const float*)d_in[3];
  const float* bk = (const float*)d_in[4];
  const float* Wv = (const float*)d_in[5];
  const float* bv = (const float*)d_in[6];
  char* ws = (char*)d_ws;

  pack_kernel<<<320, 256, 0, stream>>>(Wq, bq, Wk, bk, Wv, bv, ws);
  proj_kernel<<<dim3(32, 16), 256, 0, stream>>>(x, ws);
  attn_kernel<<<512, 256, 0, stream>>>(x, ws, (float*)d_out);
}

// Round 3
// 209.480 us; speedup vs baseline: 5.9097x; 1.3100x over previous
//
#include <hip/hip_runtime.h>
#include <math.h>

typedef __attribute__((ext_vector_type(8)))  short          short8;
typedef __attribute__((ext_vector_type(8)))  unsigned short ushort8;
typedef __attribute__((ext_vector_type(16))) float          f32x16;

#define Bb 16
#define Cc 256
#define Tt 2048

// ---- workspace layout (bytes) ----
#define WH_OFF    0u                         // ushort [320][256] bf16-hi of W
#define WL_OFF    163840u                    // ushort [320][256] bf16-lo of W
#define BALL_OFF  327680u                    // fp32 [320]
#define QTHI_OFF  328960u                    // ushort [16][2048][32]  (bf16 bits, [t][c])
#define QTLO_OFF  (QTHI_OFF + 2097152u)
#define KTHI_OFF  (QTLO_OFF + 2097152u)
#define KTLO_OFF  (KTHI_OFF + 2097152u)
#define VBF_OFF   (KTLO_OFF + 2097152u)      // ushort [16][256][2048] (bf16 bits, [c][t])

__device__ __forceinline__ unsigned short f2bf(float f) {
  union { float f; unsigned u; } v; v.f = f;
  unsigned r = v.u + 0x7fffu + ((v.u >> 16) & 1u);   // RNE
  return (unsigned short)(r >> 16);
}
__device__ __forceinline__ float bf2f(unsigned short h) {
  union { unsigned u; float f; } v; v.u = ((unsigned)h) << 16;
  return v.f;
}

// ---------------------------------------------------------------------------
// pack: W -> bf16 hi/lo planes [320][256] (+ bias fp32[320]).
// o<32: Wq, o<64: Wk, else Wv.
// ---------------------------------------------------------------------------
__global__ __launch_bounds__(256) void pack_kernel(
    const float* __restrict__ Wq, const float* __restrict__ bq,
    const float* __restrict__ Wk, const float* __restrict__ bk,
    const float* __restrict__ Wv, const float* __restrict__ bv,
    char* ws) {
  unsigned short* WH = (unsigned short*)(ws + WH_OFF);
  unsigned short* WL = (unsigned short*)(ws + WL_OFF);
  float* ball = (float*)(ws + BALL_OFF);
  int o = blockIdx.x, c = threadIdx.x;
  float v;
  if (o < 32)      v = Wq[o * 256 + c];
  else if (o < 64) v = Wk[(o - 32) * 256 + c];
  else             v = Wv[(o - 64) * 256 + c];
  unsigned short hb = f2bf(v);
  WH[o * 256 + c] = hb;
  WL[o * 256 + c] = f2bf(v - bf2f(hb));
  if (c == 0) ball[o] = (o < 32) ? bq[o] : (o < 64 ? bk[o - 32] : bv[o - 64]);
}

// ---------------------------------------------------------------------------
// proj (MFMA): O[320][64] = W[320][256] @ x[:, t0:t0+64] per (b, t-tile).
// k split in two 128-c halves: stage x fp32 -> LDS, transpose to [t][c] bf16
// hi/lo, then MFMA. A-frags (W hi/lo) straight from global (L2-resident).
// Q/K rows (o<64): 3-term hi/lo split -> fp32-class precision; V: single bf16.
// Wave w: QK o-tile (w>>1), t-tile (w&1), V o-tiles {2j+(w>>1)}.
// Outputs byte-identical layout to round 2 (attn unchanged).
// ---------------------------------------------------------------------------
__global__ __launch_bounds__(256, 2) void proj_kernel(
    const float* __restrict__ x, char* ws) {
  __shared__ __align__(16) float xs[128 * 64];                 // 32 KB, [c][t]
  __shared__ __align__(16) unsigned short xth[64 * 136];       // 17 KB, [t][c+pad]
  __shared__ __align__(16) unsigned short xtl[64 * 136];       // 17 KB

  const unsigned short* WH = (const unsigned short*)(ws + WH_OFF);
  const unsigned short* WL = (const unsigned short*)(ws + WL_OFF);
  const float* ball = (const float*)(ws + BALL_OFF);
  unsigned short* Qthi = (unsigned short*)(ws + QTHI_OFF);
  unsigned short* Qtlo = (unsigned short*)(ws + QTLO_OFF);
  unsigned short* Kthi = (unsigned short*)(ws + KTHI_OFF);
  unsigned short* Ktlo = (unsigned short*)(ws + KTLO_OFF);
  unsigned short* Vbf  = (unsigned short*)(ws + VBF_OFF);

  const int b   = blockIdx.y;
  const int t0  = blockIdx.x * 64;
  const int tid = threadIdx.x;
  const int w    = tid >> 6;
  const int lane = tid & 63;
  const int m    = lane & 31;
  const int hh   = lane >> 5;

  const float* xb = x + ((size_t)b * 256) * 2048 + t0;

  f32x16 qkacc;
  f32x16 vacc[4];
  #pragma unroll
  for (int r = 0; r < 16; ++r) qkacc[r] = 0.f;
  #pragma unroll
  for (int j = 0; j < 4; ++j)
    #pragma unroll
    for (int r = 0; r < 16; ++r) vacc[j][r] = 0.f;

  // ---- stage half 0 (c 0..127), coalesced float4 ----
  #pragma unroll
  for (int r = 0; r < 8; ++r) {
    int idx = r * 256 + tid;
    int c = idx >> 4, f = idx & 15;
    *(float4*)&xs[c * 64 + 4 * f] = *(const float4*)&xb[(size_t)c * 2048 + 4 * f];
  }
  __syncthreads();

  const int tt = w & 1;           // t-tile of this wave
  const int qo = 32 * (w >> 1);   // QK o-base (0=Q rows, 32=K rows)

  #pragma unroll
  for (int half = 0; half < 2; ++half) {
    // ---- transpose+split: xs[c][t] -> xth/xtl[t][c] (wave-uniform c-range) ----
    {
      const int t = lane;          // 0..63
      const int cq = w * 32;       // wave-uniform 32-c slab
      #pragma unroll
      for (int g = 0; g < 4; ++g) {
        ushort8 h8, l8;
        #pragma unroll
        for (int j = 0; j < 8; ++j) {
          float v = xs[(cq + g * 8 + j) * 64 + t];
          unsigned short hb = f2bf(v);
          h8[j] = hb;
          l8[j] = f2bf(v - bf2f(hb));
        }
        *(ushort8*)&xth[t * 136 + cq + g * 8] = h8;
        *(ushort8*)&xtl[t * 136 + cq + g * 8] = l8;
      }
    }
    __syncthreads();

    // ---- prefetch next half's x into regs (overlaps MFMA below) ----
    float4 pre[8];
    if (half == 0) {
      #pragma unroll
      for (int r = 0; r < 8; ++r) {
        int idx = r * 256 + tid;
        int c = idx >> 4, f = idx & 15;
        pre[r] = *(const float4*)&xb[(size_t)(128 + c) * 2048 + 4 * f];
      }
    }

    // ---- MFMA over this half's 128 c (8 k-steps of 16) ----
    #pragma unroll
    for (int kk = 0; kk < 8; ++kk) {
      const int kl = kk * 16 + 8 * hh;          // local c for B frags
      const int kg = half * 128 + kl;           // global c for A frags
      short8 bh = *(const short8*)&xth[(32 * tt + m) * 136 + kl];
      short8 bl = *(const short8*)&xtl[(32 * tt + m) * 136 + kl];
      short8 ah = *(const short8*)&WH[(size_t)(qo + m) * 256 + kg];
      short8 al = *(const short8*)&WL[(size_t)(qo + m) * 256 + kg];
      qkacc = __builtin_amdgcn_mfma_f32_32x32x16_bf16(ah, bh, qkacc, 0, 0, 0);
      qkacc = __builtin_amdgcn_mfma_f32_32x32x16_bf16(ah, bl, qkacc, 0, 0, 0);
      qkacc = __builtin_amdgcn_mfma_f32_32x32x16_bf16(al, bh, qkacc, 0, 0, 0);
      #pragma unroll
      for (int j = 0; j < 4; ++j) {
        short8 av = *(const short8*)&WH[(size_t)(64 + 32 * (2 * j + (w >> 1)) + m) * 256 + kg];
        vacc[j] = __builtin_amdgcn_mfma_f32_32x32x16_bf16(av, bh, vacc[j], 0, 0, 0);
      }
    }

    if (half == 0) {
      // land prefetch into xs (xs is free: transpose of half0 done pre-barrier)
      #pragma unroll
      for (int r = 0; r < 8; ++r) {
        int idx = r * 256 + tid;
        int c = idx >> 4, f = idx & 15;
        *(float4*)&xs[c * 64 + 4 * f] = pre[r];
      }
      __syncthreads();   // xth consumed by all waves + new xs visible
    }
  }

  // ---- epilogue ----
  // Q/K tile: bias in fp32, then hi/lo split store ([b][t][32] planes)
  {
    unsigned short* ph = (w < 2) ? Qthi : Kthi;
    unsigned short* pl = (w < 2) ? Qtlo : Ktlo;
    const int tcol = t0 + 32 * tt + m;
    #pragma unroll
    for (int r = 0; r < 16; ++r) {
      int orow = (r & 3) + 8 * (r >> 2) + 4 * hh;      // 0..31 within tile
      float v = qkacc[r] + ball[qo + orow];
      unsigned short hb = f2bf(v);
      size_t a = ((size_t)b * 2048 + tcol) * 32 + orow;
      ph[a] = hb;
      pl[a] = f2bf(v - bf2f(hb));
    }
  }
  // V tiles: bias + bf16 store ([b][c][t], lane-contiguous in t)
  #pragma unroll
  for (int j = 0; j < 4; ++j) {
    const int vob = 64 + 32 * (2 * j + (w >> 1));
    #pragma unroll
    for (int r = 0; r < 16; ++r) {
      int orow = (r & 3) + 8 * (r >> 2) + 4 * hh;
      int o = vob + orow;
      float v = vacc[j][r] + ball[o];
      Vbf[((size_t)b * 256 + (o - 64)) * 2048 + t0 + 32 * tt + m] = f2bf(v);
    }
  }
}

// ---------------------------------------------------------------------------
// attn: flash-style, MFMA 32x32x16 bf16.  (UNCHANGED from round 2)
// ---------------------------------------------------------------------------
__global__ __launch_bounds__(256, 2) void attn_kernel(
    const float* __restrict__ x, const char* __restrict__ ws,
    float* __restrict__ out) {
  __shared__ __align__(16) unsigned short Qsh[64 * 40], Qsl[64 * 40];
  __shared__ __align__(16) unsigned short Ksh[32 * 40], Ksl[32 * 40];
  __shared__ __align__(16) unsigned short Ps[64 * 40];
  __shared__ __align__(16) unsigned short Vs[256 * 40];
  __shared__ float sums[64];
  __shared__ float invs[64];

  const unsigned short* Qthi = (const unsigned short*)(ws + QTHI_OFF);
  const unsigned short* Qtlo = (const unsigned short*)(ws + QTLO_OFF);
  const unsigned short* Kthi = (const unsigned short*)(ws + KTHI_OFF);
  const unsigned short* Ktlo = (const unsigned short*)(ws + KTLO_OFF);

  const int id = blockIdx.x;
  const int b  = ((id & 7) << 1) | ((id >> 3) & 1);   // 2 batches per XCD
  const int qt = id >> 4;
  const int t0 = qt * 64;
  const int tid  = threadIdx.x;
  const int w    = tid >> 6;
  const int lane = tid & 63;
  const int m    = lane & 31;
  const int hh   = lane >> 5;

  const unsigned short* Vg =
      (const unsigned short*)(ws + VBF_OFF) + (size_t)b * 256 * 2048;

  // stage Q tile once: [64 q][32 c] hi+lo
  {
    int rr = tid >> 2, cq = tid & 3;
    size_t g = ((size_t)b * 2048 + t0 + rr) * 32 + cq * 8;
    *(ushort8*)&Qsh[rr * 40 + cq * 8] = *(const ushort8*)&Qthi[g];
    *(ushort8*)&Qsl[rr * 40 + cq * 8] = *(const ushort8*)&Qtlo[g];
  }

  f32x16 pacc[2][2];   // [q-tile n][c-tile mi]
  #pragma unroll
  for (int n = 0; n < 2; ++n)
    #pragma unroll
    for (int mi = 0; mi < 2; ++mi)
      #pragma unroll
      for (int r = 0; r < 16; ++r) pacc[n][mi][r] = 0.f;
  float sacc[16];
  #pragma unroll
  for (int r = 0; r < 16; ++r) sacc[r] = 0.f;

  for (int it = 0; it < 64; ++it) {
    const int sb = it * 32;
    __syncthreads();   // prev iter's PV done with Ks/Vs/Ps

    // stage K tile [32 s][32 c] hi+lo
    {
      int p = tid >> 7, rr = (tid >> 2) & 31, cq = tid & 3;
      size_t g = ((size_t)b * 2048 + sb + rr) * 32 + cq * 8;
      const unsigned short* src = p ? Ktlo : Kthi;
      unsigned short* dst = p ? Ksl : Ksh;
      *(ushort8*)&dst[rr * 40 + cq * 8] = *(const ushort8*)&src[g];
    }
    // stage V tile [256 c][32 s]
    #pragma unroll
    for (int r = 0; r < 4; ++r) {
      int idx = r * 256 + tid;
      int c = idx >> 2, k = idx & 3;
      *(ushort8*)&Vs[c * 40 + k * 8] = *(const ushort8*)&Vg[(size_t)c * 2048 + sb + k * 8];
    }
    __syncthreads();

    if (w < 2) {   // QK + exp on waves 0,1
      f32x16 qacc;
      #pragma unroll
      for (int r = 0; r < 16; ++r) qacc[r] = 0.f;
      #pragma unroll
      for (int ks = 0; ks < 2; ++ks) {
        short8 ah = *(const short8*)&Qsh[(32 * w + m) * 40 + ks * 16 + hh * 8];
        short8 al = *(const short8*)&Qsl[(32 * w + m) * 40 + ks * 16 + hh * 8];
        short8 bh = *(const short8*)&Ksh[m * 40 + ks * 16 + hh * 8];
        short8 bl = *(const short8*)&Ksl[m * 40 + ks * 16 + hh * 8];
        qacc = __builtin_amdgcn_mfma_f32_32x32x16_bf16(ah, bh, qacc, 0, 0, 0);
        qacc = __builtin_amdgcn_mfma_f32_32x32x16_bf16(ah, bl, qacc, 0, 0, 0);
        qacc = __builtin_amdgcn_mfma_f32_32x32x16_bf16(al, bh, qacc, 0, 0, 0);
      }
      #pragma unroll
      for (int r = 0; r < 16; ++r) {
        float e = __expf(qacc[r]);
        unsigned short hb = f2bf(e);
        sacc[r] += bf2f(hb);   // sum the rounded value -> exact normalization
        int q = 32 * w + (r & 3) + 8 * (r >> 2) + 4 * hh;
        Ps[q * 40 + m] = hb;
      }
    }
    __syncthreads();

    // PV: D[c][q] += V[c][s] * P[q][s]
    #pragma unroll
    for (int ks = 0; ks < 2; ++ks) {
      short8 p0 = *(const short8*)&Ps[m * 40 + ks * 16 + hh * 8];
      short8 p1 = *(const short8*)&Ps[(32 + m) * 40 + ks * 16 + hh * 8];
      short8 v0 = *(const short8*)&Vs[(32 * w + m) * 40 + ks * 16 + hh * 8];
      short8 v1 = *(const short8*)&Vs[(32 * (w + 4) + m) * 40 + ks * 16 + hh * 8];
      pacc[0][0] = __builtin_amdgcn_mfma_f32_32x32x16_bf16(v0, p0, pacc[0][0], 0, 0, 0);
      pacc[0][1] = __builtin_amdgcn_mfma_f32_32x32x16_bf16(v1, p0, pacc[0][1], 0, 0, 0);
      pacc[1][0] = __builtin_amdgcn_mfma_f32_32x32x16_bf16(v0, p1, pacc[1][0], 0, 0, 0);
      pacc[1][1] = __builtin_amdgcn_mfma_f32_32x32x16_bf16(v1, p1, pacc[1][1], 0, 0, 0);
    }
  }

  // row sums -> inv
  if (w < 2) {
    #pragma unroll
    for (int r = 0; r < 16; ++r) {
      float v = sacc[r];
      #pragma unroll
      for (int off = 1; off < 32; off <<= 1) v += __shfl_xor(v, off, 64);
      if (m == 0) sums[32 * w + (r & 3) + 8 * (r >> 2) + 4 * hh] = v;
    }
  }
  __syncthreads();
  if (tid < 64) invs[tid] = 1.0f / sums[tid];
  __syncthreads();

  // epilogue: out = pacc/sum + x, coalesced along t (col = q)
  const float inv0 = invs[m], inv1 = invs[32 + m];
  #pragma unroll
  for (int n = 0; n < 2; ++n) {
    const float inv = n ? inv1 : inv0;
    const int q = 32 * n + m;
    #pragma unroll
    for (int mi = 0; mi < 2; ++mi) {
      const int cbase = 32 * (w + 4 * mi);
      #pragma unroll
      for (int r = 0; r < 16; ++r) {
        int c = cbase + (r & 3) + 8 * (r >> 2) + 4 * hh;
        size_t a = ((size_t)b * 256 + c) * 2048 + t0 + q;
        out[a] = pacc[n][mi][r] * inv + x[a];
      }
    }
  }
}

// ---------------------------------------------------------------------------
extern "C" void kernel_launch(void* const* d_in, const int* in_sizes, int n_in,
                              void* d_out, int out_size, void* d_ws, size_t ws_size,
                              hipStream_t stream) {
  const float* x  = (const float*)d_in[0];
  const float* Wq = (const float*)d_in[1];
  const float* bq = (const float*)d_in[2];
  const float* Wk = (const float*)d_in[3];
  const float* bk = (const float*)d_in[4];
  const float* Wv = (const float*)d_in[5];
  const float* bv = (const float*)d_in[6];
  char* ws = (char*)d_ws;

  pack_kernel<<<320, 256, 0, stream>>>(Wq, bq, Wk, bk, Wv, bv, ws);
  proj_kernel<<<dim3(32, 16), 256, 0, stream>>>(x, ws);
  attn_kernel<<<512, 256, 0, stream>>>(x, ws, (float*)d_out);
}

// Round 4
// 194.646 us; speedup vs baseline: 6.3601x; 1.0762x over previous
//
#include <hip/hip_runtime.h>
#include <math.h>

typedef __attribute__((ext_vector_type(8)))  short          short8;
typedef __attribute__((ext_vector_type(8)))  unsigned short ushort8;
typedef __attribute__((ext_vector_type(16))) float          f32x16;

#define Bb 16
#define Cc 256
#define Tt 2048

// ---- workspace layout (bytes) ----
#define WH_OFF    0u                         // ushort [320][256] bf16-hi of W
#define WL_OFF    163840u                    // ushort [320][256] bf16-lo of W
#define BALL_OFF  327680u                    // fp32 [320]
#define QTHI_OFF  328960u                    // ushort [16][2048][32]  (bf16 bits, [t][c])
#define QTLO_OFF  (QTHI_OFF + 2097152u)
#define KTHI_OFF  (QTLO_OFF + 2097152u)
#define KTLO_OFF  (KTHI_OFF + 2097152u)
#define VBF_OFF   (KTLO_OFF + 2097152u)      // ushort [16][256][2048] (bf16 bits, [c][t])

__device__ __forceinline__ unsigned short f2bf(float f) {
  union { float f; unsigned u; } v; v.f = f;
  unsigned r = v.u + 0x7fffu + ((v.u >> 16) & 1u);   // RNE
  return (unsigned short)(r >> 16);
}
__device__ __forceinline__ float bf2f(unsigned short h) {
  union { unsigned u; float f; } v; v.u = ((unsigned)h) << 16;
  return v.f;
}

// Swizzled LDS addressing: rows of 128B = 8 units of 16B; unit u lives at
// 16B-slot (u ^ (row&7)). Conflict-free for both lane-sweeps-unit staging
// stores and fixed-unit/row-sweep frag reads.
__device__ __forceinline__ unsigned short* swz(unsigned short* base, int row, int u) {
  return base + row * 64 + ((u ^ (row & 7)) << 3);
}
__device__ __forceinline__ const unsigned short* swzc(const unsigned short* base, int row, int u) {
  return base + row * 64 + ((u ^ (row & 7)) << 3);
}

// ---------------------------------------------------------------------------
// pack: W -> bf16 hi/lo planes [320][256] (+ bias fp32[320]).  (unchanged)
// ---------------------------------------------------------------------------
__global__ __launch_bounds__(256) void pack_kernel(
    const float* __restrict__ Wq, const float* __restrict__ bq,
    const float* __restrict__ Wk, const float* __restrict__ bk,
    const float* __restrict__ Wv, const float* __restrict__ bv,
    char* ws) {
  unsigned short* WH = (unsigned short*)(ws + WH_OFF);
  unsigned short* WL = (unsigned short*)(ws + WL_OFF);
  float* ball = (float*)(ws + BALL_OFF);
  int o = blockIdx.x, c = threadIdx.x;
  float v;
  if (o < 32)      v = Wq[o * 256 + c];
  else if (o < 64) v = Wk[(o - 32) * 256 + c];
  else             v = Wv[(o - 64) * 256 + c];
  unsigned short hb = f2bf(v);
  WH[o * 256 + c] = hb;
  WL[o * 256 + c] = f2bf(v - bf2f(hb));
  if (c == 0) ball[o] = (o < 32) ? bq[o] : (o < 64 ? bk[o - 32] : bv[o - 64]);
}

// ---------------------------------------------------------------------------
// proj (MFMA): unchanged from round 3.
// ---------------------------------------------------------------------------
__global__ __launch_bounds__(256, 2) void proj_kernel(
    const float* __restrict__ x, char* ws) {
  __shared__ __align__(16) float xs[128 * 64];
  __shared__ __align__(16) unsigned short xth[64 * 136];
  __shared__ __align__(16) unsigned short xtl[64 * 136];

  const unsigned short* WH = (const unsigned short*)(ws + WH_OFF);
  const unsigned short* WL = (const unsigned short*)(ws + WL_OFF);
  const float* ball = (const float*)(ws + BALL_OFF);
  unsigned short* Qthi = (unsigned short*)(ws + QTHI_OFF);
  unsigned short* Qtlo = (unsigned short*)(ws + QTLO_OFF);
  unsigned short* Kthi = (unsigned short*)(ws + KTHI_OFF);
  unsigned short* Ktlo = (unsigned short*)(ws + KTLO_OFF);
  unsigned short* Vbf  = (unsigned short*)(ws + VBF_OFF);

  const int b   = blockIdx.y;
  const int t0  = blockIdx.x * 64;
  const int tid = threadIdx.x;
  const int w    = tid >> 6;
  const int lane = tid & 63;
  const int m    = lane & 31;
  const int hh   = lane >> 5;

  const float* xb = x + ((size_t)b * 256) * 2048 + t0;

  f32x16 qkacc;
  f32x16 vacc[4];
  #pragma unroll
  for (int r = 0; r < 16; ++r) qkacc[r] = 0.f;
  #pragma unroll
  for (int j = 0; j < 4; ++j)
    #pragma unroll
    for (int r = 0; r < 16; ++r) vacc[j][r] = 0.f;

  #pragma unroll
  for (int r = 0; r < 8; ++r) {
    int idx = r * 256 + tid;
    int c = idx >> 4, f = idx & 15;
    *(float4*)&xs[c * 64 + 4 * f] = *(const float4*)&xb[(size_t)c * 2048 + 4 * f];
  }
  __syncthreads();

  const int tt = w & 1;
  const int qo = 32 * (w >> 1);

  #pragma unroll
  for (int half = 0; half < 2; ++half) {
    {
      const int t = lane;
      const int cq = w * 32;
      #pragma unroll
      for (int g = 0; g < 4; ++g) {
        ushort8 h8, l8;
        #pragma unroll
        for (int j = 0; j < 8; ++j) {
          float v = xs[(cq + g * 8 + j) * 64 + t];
          unsigned short hb = f2bf(v);
          h8[j] = hb;
          l8[j] = f2bf(v - bf2f(hb));
        }
        *(ushort8*)&xth[t * 136 + cq + g * 8] = h8;
        *(ushort8*)&xtl[t * 136 + cq + g * 8] = l8;
      }
    }
    __syncthreads();

    float4 pre[8];
    if (half == 0) {
      #pragma unroll
      for (int r = 0; r < 8; ++r) {
        int idx = r * 256 + tid;
        int c = idx >> 4, f = idx & 15;
        pre[r] = *(const float4*)&xb[(size_t)(128 + c) * 2048 + 4 * f];
      }
    }

    #pragma unroll
    for (int kk = 0; kk < 8; ++kk) {
      const int kl = kk * 16 + 8 * hh;
      const int kg = half * 128 + kl;
      short8 bh = *(const short8*)&xth[(32 * tt + m) * 136 + kl];
      short8 bl = *(const short8*)&xtl[(32 * tt + m) * 136 + kl];
      short8 ah = *(const short8*)&WH[(size_t)(qo + m) * 256 + kg];
      short8 al = *(const short8*)&WL[(size_t)(qo + m) * 256 + kg];
      qkacc = __builtin_amdgcn_mfma_f32_32x32x16_bf16(ah, bh, qkacc, 0, 0, 0);
      qkacc = __builtin_amdgcn_mfma_f32_32x32x16_bf16(ah, bl, qkacc, 0, 0, 0);
      qkacc = __builtin_amdgcn_mfma_f32_32x32x16_bf16(al, bh, qkacc, 0, 0, 0);
      #pragma unroll
      for (int j = 0; j < 4; ++j) {
        short8 av = *(const short8*)&WH[(size_t)(64 + 32 * (2 * j + (w >> 1)) + m) * 256 + kg];
        vacc[j] = __builtin_amdgcn_mfma_f32_32x32x16_bf16(av, bh, vacc[j], 0, 0, 0);
      }
    }

    if (half == 0) {
      #pragma unroll
      for (int r = 0; r < 8; ++r) {
        int idx = r * 256 + tid;
        int c = idx >> 4, f = idx & 15;
        *(float4*)&xs[c * 64 + 4 * f] = pre[r];
      }
      __syncthreads();
    }
  }

  {
    unsigned short* ph = (w < 2) ? Qthi : Kthi;
    unsigned short* pl = (w < 2) ? Qtlo : Ktlo;
    const int tcol = t0 + 32 * tt + m;
    #pragma unroll
    for (int r = 0; r < 16; ++r) {
      int orow = (r & 3) + 8 * (r >> 2) + 4 * hh;
      float v = qkacc[r] + ball[qo + orow];
      unsigned short hb = f2bf(v);
      size_t a = ((size_t)b * 2048 + tcol) * 32 + orow;
      ph[a] = hb;
      pl[a] = f2bf(v - bf2f(hb));
    }
  }
  #pragma unroll
  for (int j = 0; j < 4; ++j) {
    const int vob = 64 + 32 * (2 * j + (w >> 1));
    #pragma unroll
    for (int r = 0; r < 16; ++r) {
      int orow = (r & 3) + 8 * (r >> 2) + 4 * hh;
      int o = vob + orow;
      float v = vacc[j][r] + ball[o];
      Vbf[((size_t)b * 256 + (o - 64)) * 2048 + t0 + 32 * tt + m] = f2bf(v);
    }
  }
}

// ---------------------------------------------------------------------------
// attn v2: s-tile 64, 32 iterations, all-wave QK, register prefetch of next
// K/V tile, XOR-swizzled LDS (conflict-free staging + frag access).
// Wave w: QK tile (q-tile n=w>>1, s-tile u=w&1); PV c-tiles {w, w+4} x both q.
// Numerics identical to round 3 (3-term hi/lo QK, bf16 P/V, rounded-P sums).
// ---------------------------------------------------------------------------
__global__ __launch_bounds__(256, 2) void attn_kernel(
    const float* __restrict__ x, const char* __restrict__ ws,
    float* __restrict__ out) {
  __shared__ __align__(16) unsigned short Qs[64 * 64];   // [q][hi c0-31 | lo c0-31]
  __shared__ __align__(16) unsigned short Ks[64 * 64];   // [s][hi | lo]
  __shared__ __align__(16) unsigned short Ps[64 * 64];   // [q][s0-63]
  __shared__ __align__(16) unsigned short Vs[256 * 64];  // [c][s0-63]
  __shared__ float sums[64][2];
  __shared__ float invs[64];

  const unsigned short* Qthi = (const unsigned short*)(ws + QTHI_OFF);
  const unsigned short* Qtlo = (const unsigned short*)(ws + QTLO_OFF);
  const unsigned short* Kthi = (const unsigned short*)(ws + KTHI_OFF);
  const unsigned short* Ktlo = (const unsigned short*)(ws + KTLO_OFF);

  const int id = blockIdx.x;
  const int b  = ((id & 7) << 1) | ((id >> 3) & 1);   // 2 batches per XCD
  const int qt = id >> 4;
  const int t0 = qt * 64;
  const int tid  = threadIdx.x;
  const int w    = tid >> 6;
  const int lane = tid & 63;
  const int m    = lane & 31;
  const int hh   = lane >> 5;
  const int n    = w >> 1;       // q-tile for QK
  const int u    = w & 1;        // s-tile for QK

  const unsigned short* Vg =
      (const unsigned short*)(ws + VBF_OFF) + (size_t)b * 256 * 2048;

  // staging coords: K/Q chunk = (row krr, 16B col kcq); V chunk = (row c, unit vk)
  const int krr = (tid >> 2) & 63, kcq = tid & 3;
  const int vk  = tid & 7,  vc = tid >> 3;     // V row base c = r*32 + vc

  // ---- stage Q (persistent) + K/V for iter 0 ----
  #pragma unroll
  for (int p = 0; p < 2; ++p) {
    const unsigned short* src = p ? Qtlo : Qthi;
    *(ushort8*)swz(Qs, krr, p * 4 + kcq) =
        *(const ushort8*)&src[((size_t)b * 2048 + t0 + krr) * 32 + kcq * 8];
  }
  #pragma unroll
  for (int p = 0; p < 2; ++p) {
    const unsigned short* src = p ? Ktlo : Kthi;
    *(ushort8*)swz(Ks, krr, p * 4 + kcq) =
        *(const ushort8*)&src[((size_t)b * 2048 + krr) * 32 + kcq * 8];
  }
  #pragma unroll
  for (int r = 0; r < 8; ++r) {
    int c = r * 32 + vc;
    *(ushort8*)swz(Vs, c, vk) = *(const ushort8*)&Vg[(size_t)c * 2048 + vk * 8];
  }
  __syncthreads();

  f32x16 pacc[2][2];
  #pragma unroll
  for (int a = 0; a < 2; ++a)
    #pragma unroll
    for (int d = 0; d < 2; ++d)
      #pragma unroll
      for (int r = 0; r < 16; ++r) pacc[a][d][r] = 0.f;
  float sacc[16];
  #pragma unroll
  for (int r = 0; r < 16; ++r) sacc[r] = 0.f;

  ushort8 kpre[2], vpre[8];

  for (int it = 0; it < 32; ++it) {
    // ---- prefetch next K/V tile into regs (completes under QK+PV) ----
    if (it < 31) {
      const int sb2 = it * 64 + 64;
      #pragma unroll
      for (int p = 0; p < 2; ++p) {
        const unsigned short* src = p ? Ktlo : Kthi;
        kpre[p] = *(const ushort8*)&src[((size_t)b * 2048 + sb2 + krr) * 32 + kcq * 8];
      }
      #pragma unroll
      for (int r = 0; r < 8; ++r) {
        int c = r * 32 + vc;
        vpre[r] = *(const ushort8*)&Vg[(size_t)c * 2048 + sb2 + vk * 8];
      }
    }

    // ---- QK (one 32x32 tile per wave) + exp -> Ps ----
    {
      f32x16 qacc;
      #pragma unroll
      for (int r = 0; r < 16; ++r) qacc[r] = 0.f;
      #pragma unroll
      for (int ks = 0; ks < 2; ++ks) {
        short8 ah = *(const short8*)swzc(Qs, 32 * n + m, ks * 2 + hh);
        short8 al = *(const short8*)swzc(Qs, 32 * n + m, 4 + ks * 2 + hh);
        short8 bh = *(const short8*)swzc(Ks, 32 * u + m, ks * 2 + hh);
        short8 bl = *(const short8*)swzc(Ks, 32 * u + m, 4 + ks * 2 + hh);
        qacc = __builtin_amdgcn_mfma_f32_32x32x16_bf16(ah, bh, qacc, 0, 0, 0);
        qacc = __builtin_amdgcn_mfma_f32_32x32x16_bf16(ah, bl, qacc, 0, 0, 0);
        qacc = __builtin_amdgcn_mfma_f32_32x32x16_bf16(al, bh, qacc, 0, 0, 0);
      }
      const int sc = 32 * u + m;
      #pragma unroll
      for (int r = 0; r < 16; ++r) {
        float e = __expf(qacc[r]);
        unsigned short hb = f2bf(e);
        sacc[r] += bf2f(hb);
        int qq = 32 * n + (r & 3) + 8 * (r >> 2) + 4 * hh;
        Ps[qq * 64 + (((sc >> 3) ^ (qq & 7)) << 3) + (sc & 7)] = hb;
      }
    }
    __syncthreads();

    // ---- PV: D[c][q] += V[c][s] * P[q][s], 4 k-steps over s=64 ----
    #pragma unroll
    for (int ks = 0; ks < 4; ++ks) {
      short8 p0 = *(const short8*)swzc(Ps, m,      ks * 2 + hh);
      short8 p1 = *(const short8*)swzc(Ps, 32 + m, ks * 2 + hh);
      short8 v0 = *(const short8*)swzc(Vs, 32 * w + m,       ks * 2 + hh);
      short8 v1 = *(const short8*)swzc(Vs, 32 * (w + 4) + m, ks * 2 + hh);
      pacc[0][0] = __builtin_amdgcn_mfma_f32_32x32x16_bf16(v0, p0, pacc[0][0], 0, 0, 0);
      pacc[0][1] = __builtin_amdgcn_mfma_f32_32x32x16_bf16(v1, p0, pacc[0][1], 0, 0, 0);
      pacc[1][0] = __builtin_amdgcn_mfma_f32_32x32x16_bf16(v0, p1, pacc[1][0], 0, 0, 0);
      pacc[1][1] = __builtin_amdgcn_mfma_f32_32x32x16_bf16(v1, p1, pacc[1][1], 0, 0, 0);
    }
    __syncthreads();

    // ---- land prefetched tiles into LDS ----
    if (it < 31) {
      #pragma unroll
      for (int p = 0; p < 2; ++p)
        *(ushort8*)swz(Ks, krr, p * 4 + kcq) = kpre[p];
      #pragma unroll
      for (int r = 0; r < 8; ++r)
        *(ushort8*)swz(Vs, r * 32 + vc, vk) = vpre[r];
      __syncthreads();
    }
  }

  // ---- row sums: reduce over m within wave, combine s-halves via LDS ----
  #pragma unroll
  for (int r = 0; r < 16; ++r) {
    float v = sacc[r];
    #pragma unroll
    for (int off = 1; off < 32; off <<= 1) v += __shfl_xor(v, off, 64);
    if (m == 0) sums[32 * n + (r & 3) + 8 * (r >> 2) + 4 * hh][u] = v;
  }
  __syncthreads();
  if (tid < 64) invs[tid] = 1.0f / (sums[tid][0] + sums[tid][1]);
  __syncthreads();

  // ---- epilogue: out = pacc/sum + x, coalesced along t (col = q) ----
  const float inv0 = invs[m], inv1 = invs[32 + m];
  #pragma unroll
  for (int nn = 0; nn < 2; ++nn) {
    const float inv = nn ? inv1 : inv0;
    const int q = 32 * nn + m;
    #pragma unroll
    for (int mi = 0; mi < 2; ++mi) {
      const int cbase = 32 * (w + 4 * mi);
      #pragma unroll
      for (int r = 0; r < 16; ++r) {
        int c = cbase + (r & 3) + 8 * (r >> 2) + 4 * hh;
        size_t a = ((size_t)b * 256 + c) * 2048 + t0 + q;
        out[a] = pacc[nn][mi][r] * inv + x[a];
      }
    }
  }
}

// ---------------------------------------------------------------------------
extern "C" void kernel_launch(void* const* d_in, const int* in_sizes, int n_in,
                              void* d_out, int out_size, void* d_ws, size_t ws_size,
                              hipStream_t stream) {
  const float* x  = (const float*)d_in[0];
  const float* Wq = (const float*)d_in[1];
  const float* bq = (const float*)d_in[2];
  const float* Wk = (const float*)d_in[3];
  const float* bk = (const float*)d_in[4];
  const float* Wv = (const float*)d_in[5];
  const float* bv = (const float*)d_in[6];
  char* ws = (char*)d_ws;

  pack_kernel<<<320, 256, 0, stream>>>(Wq, bq, Wk, bk, Wv, bv, ws);
  proj_kernel<<<dim3(32, 16), 256, 0, stream>>>(x, ws);
  attn_kernel<<<512, 256, 0, stream>>>(x, ws, (float*)d_out);
}